// Round 8
// baseline (242.888 us; speedup 1.0000x reference)
//
#include <hip/hip_runtime.h>
#include <stdint.h>
#include <stddef.h>

// ---------------------------------------------------------------------------
// HHGNN: x = LN(route_by_type(embeds @ W[t] + b[t], mask)) ;
//        lat = adj^T @ x ; ret = adj @ lat
// Shapes: B=8, N=4096, M=2048, H=128, T=13. adj fp32 [B][N][M].
// R8 vs R7/R5: the GEMMs were fabric-BW bound on B-panel RE-STREAMING
// (BM=32 -> every block re-reads the whole 1MB B panel; 512MB cache traffic
// per GEMM ~= the missing 2x). R6 (BM 16) was the confirming inverse.
// Fix: BM=128 tiles (B-restream 512->128MB), split-K to keep grid=512:
//  k2: 8b x 16mt x 4nc, 16 steps BK=64, fp32 partials pLat + flat reduce
//  k3: 8b x 32nt x 2kc, 16 steps, MFMA roles SWAPPED (A-op=latT h-frag,
//      B-op=adj n-frag) so C regs are h-contiguous -> f32x4 stores, flat red.
// Schedule: R5's issue-early/write-late/end-barrier (R7 proved counted-vmcnt
// adds nothing). ws: xT 8.4 + latT 4.2 + pLat 33.6 + pRet 33.6 = 79.7MB.
// ---------------------------------------------------------------------------

typedef float    f32x4_t  __attribute__((ext_vector_type(4)));
typedef __bf16   bf16x8_t __attribute__((ext_vector_type(8)));
typedef unsigned int u32x4_t __attribute__((ext_vector_type(4)));
typedef unsigned int u32x2_t __attribute__((ext_vector_type(2)));

__device__ __forceinline__ unsigned short f2bf(float f) {
    union { float f; unsigned int u; } v; v.f = f;
    unsigned int u = v.u;
    return (unsigned short)((u + 0x7FFFu + ((u >> 16) & 1u)) >> 16);
}

// packed RNE fp32x2 -> bf16x2 (lo=a, hi=b)
__device__ __forceinline__ unsigned int cvtpk(float a, float b) {
    unsigned int r;
    asm("v_cvt_pk_bf16_f32 %0, %1, %2" : "=v"(r) : "v"(a), "v"(b));
    return r;
}

__device__ __forceinline__ bool mask_on(const unsigned char* m, int gid) {
    return (m[gid] | m[(gid >> 2) << 2]) != 0;
}

// byte offset of 16B-granule g in row `row` of a [rows][64] bf16 LDS panel
__device__ __forceinline__ int foff(int row, int g) {
    return row * 128 + (((g) ^ (row & 7)) << 4);
}

// B-panel staging: 128 rows x 64 bf16 via global_load_lds, 16B/lane; LDS
// linear, swizzle realized by pre-swizzled SOURCE granule (m173 pattern).
template<int GSTRIDE>
__device__ __forceinline__ void stage_B(const unsigned short* __restrict__ gb,
                                        int k0, unsigned short* ldsB, int t)
{
    const int l = t & 63, w = t >> 6;
    const int hsub = l >> 3;
    const int csrc = ((l & 7) ^ hsub) << 3;
    #pragma unroll
    for (int i = 0; i < 4; ++i) {
        const int hbase = i * 32 + w * 8;
        const unsigned short* src = gb + (size_t)(hbase + hsub) * GSTRIDE + k0 + csrc;
        unsigned short* dst = ldsB + hbase * 64;
        __builtin_amdgcn_global_load_lds(
            (__attribute__((address_space(1))) void*)src,
            (__attribute__((address_space(3))) void*)dst, 16, 0, 0);
    }
}

// ---------------------------------------------------------------------------
// Kernel 1: per-type linear + bias + mask + LayerNorm -> xT bf16 [B][H][N]
// (unchanged from R1)
// ---------------------------------------------------------------------------
__global__ __launch_bounds__(256) void k1_typed_ln(
    const float* __restrict__ embeds,
    const int*   __restrict__ ntype,
    const unsigned char* __restrict__ mask8,
    const float* __restrict__ W,
    const float* __restrict__ bias,
    const float* __restrict__ gamma,
    const float* __restrict__ beta,
    unsigned short* __restrict__ xT)
{
    __shared__ float e_lds[128][132];
    __shared__ float W_lds[128][128];
    __shared__ float b_lds[13 * 128];
    __shared__ float g_lds[128];
    __shared__ float be_lds[128];
    __shared__ unsigned short lists[13][128];
    __shared__ int cnt[13];

    const int t   = threadIdx.x;
    const int blk = blockIdx.x;
    const int b   = blk >> 5;
    const int n0  = (blk & 31) << 7;
    const float* ebase = embeds + ((size_t)b * 4096 + n0) * 128;

    for (int it = 0; it < 16; ++it) {
        int idx = it * 256 + t;
        int n = idx >> 5, c = idx & 31;
        float4 v = *(const float4*)(ebase + n * 128 + c * 4);
        *(float4*)(&e_lds[n][c * 4]) = v;
    }
    for (int i = t; i < 13 * 128; i += 256) b_lds[i] = bias[i];
    if (t < 128) { g_lds[t] = gamma[t]; be_lds[t] = beta[t]; }
    if (t < 13) cnt[t] = 0;
    __syncthreads();

    if (t < 128) {
        int ty = ntype[(size_t)b * 4096 + n0 + t];
        int slot = atomicAdd(&cnt[ty], 1);
        lists[ty][slot] = (unsigned short)t;
    }
    __syncthreads();

    const int lane = t & 63;
    const int wv   = t >> 6;

    for (int ty = 0; ty < 13; ++ty) {
        const int c = cnt[ty];
        __syncthreads();
        if (c > 0) {
            const float* Wt = W + (size_t)ty * 128 * 128;
            for (int it = 0; it < 16; ++it) {
                int idx = it * 256 + t;
                *(float4*)(&W_lds[idx >> 5][(idx & 31) * 4]) = *(const float4*)(Wt + idx * 4);
            }
        }
        __syncthreads();
        if (c == 0) continue;

        const int ngr = (c + 3) >> 2;
        for (int g = wv; g < ngr; g += 4) {
            int base = g * 4;
            int i1 = min(base + 1, c - 1), i2 = min(base + 2, c - 1), i3 = min(base + 3, c - 1);
            int nA = lists[ty][base], nB = lists[ty][i1], nC = lists[ty][i2], nD = lists[ty][i3];
            float a0 = 0, a1 = 0, a2 = 0, a3 = 0, a4 = 0, a5 = 0, a6 = 0, a7 = 0;
            for (int h = 0; h < 128; h += 4) {
                float4 eA = *(const float4*)(&e_lds[nA][h]);
                float4 eB = *(const float4*)(&e_lds[nB][h]);
                float4 eC = *(const float4*)(&e_lds[nC][h]);
                float4 eD = *(const float4*)(&e_lds[nD][h]);
                float w0 = W_lds[h + 0][lane],      w1 = W_lds[h + 1][lane];
                float w2 = W_lds[h + 2][lane],      w3 = W_lds[h + 3][lane];
                float v0 = W_lds[h + 0][lane + 64], v1 = W_lds[h + 1][lane + 64];
                float v2 = W_lds[h + 2][lane + 64], v3 = W_lds[h + 3][lane + 64];
                a0 += eA.x * w0 + eA.y * w1 + eA.z * w2 + eA.w * w3;
                a1 += eB.x * w0 + eB.y * w1 + eB.z * w2 + eB.w * w3;
                a2 += eC.x * w0 + eC.y * w1 + eC.z * w2 + eC.w * w3;
                a3 += eD.x * w0 + eD.y * w1 + eD.z * w2 + eD.w * w3;
                a4 += eA.x * v0 + eA.y * v1 + eA.z * v2 + eA.w * v3;
                a5 += eB.x * v0 + eB.y * v1 + eB.z * v2 + eB.w * v3;
                a6 += eC.x * v0 + eC.y * v1 + eC.z * v2 + eC.w * v3;
                a7 += eD.x * v0 + eD.y * v1 + eD.z * v2 + eD.w * v3;
            }
            float bl = b_lds[ty * 128 + lane], bh = b_lds[ty * 128 + lane + 64];
            a0 += bl; a1 += bl; a2 += bl; a3 += bl;
            a4 += bh; a5 += bh; a6 += bh; a7 += bh;
            int gbase = b * 4096 + n0;
            if (mask_on(mask8, gbase + nA)) { e_lds[nA][lane] = a0; e_lds[nA][lane + 64] = a4; }
            if (mask_on(mask8, gbase + nB)) { e_lds[nB][lane] = a1; e_lds[nB][lane + 64] = a5; }
            if (mask_on(mask8, gbase + nC)) { e_lds[nC][lane] = a2; e_lds[nC][lane + 64] = a6; }
            if (mask_on(mask8, gbase + nD)) { e_lds[nD][lane] = a3; e_lds[nD][lane + 64] = a7; }
        }
    }
    __syncthreads();

    for (int i = 0; i < 32; ++i) {
        int n = wv + i * 4;
        float2 v = *(const float2*)(&e_lds[n][lane * 2]);
        float s = v.x + v.y;
        float q = v.x * v.x + v.y * v.y;
        #pragma unroll
        for (int mskw = 32; mskw >= 1; mskw >>= 1) {
            s += __shfl_xor(s, mskw);
            q += __shfl_xor(q, mskw);
        }
        float mu  = s * 0.0078125f;
        float var = q * 0.0078125f - mu * mu;
        float r   = rsqrtf(var + 1e-5f);
        float2 o;
        o.x = (v.x - mu) * r * g_lds[lane * 2]     + be_lds[lane * 2];
        o.y = (v.y - mu) * r * g_lds[lane * 2 + 1] + be_lds[lane * 2 + 1];
        *(float2*)(&e_lds[n][lane * 2]) = o;
    }
    __syncthreads();

    const int nl = t & 127;
    const int hg = t >> 7;
    unsigned short* xrow = xT + (size_t)b * 128 * 4096 + n0 + nl;
    for (int i = 0; i < 64; ++i) {
        int h = hg * 64 + i;
        xrow[(size_t)h * 4096] = f2bf(e_lds[nl][h]);
    }
}

// ---------------------------------------------------------------------------
// Kernel 2: pLat[nc][b][h][m] = sum_{n in nc} adj[b][n][m] * x[b][n][h]
// grid 512 = 8b x 16mt(128m) x 4nc(1024n). 4 waves (2m x 2h), wave 64x64.
// BK=64, 16 steps. LDS 64KB -> 2 blocks/CU.
// ---------------------------------------------------------------------------
__global__ __launch_bounds__(256) void k2_lat(
    const float* __restrict__ adj,
    const unsigned short* __restrict__ xT,
    float* __restrict__ pLat)
{
    __shared__ unsigned short Al[2][128 * 64];   // [m][k] bf16
    __shared__ unsigned short Bl[2][128 * 64];   // [h][k] bf16

    const int t   = threadIdx.x;
    const int bid = blockIdx.x;
    const int b   = bid & 7;
    const int r   = bid >> 3;
    const int m0  = (r & 15) << 7;
    const int nc  = r >> 4;
    const int nbase = nc << 10;
    const float* adjb = adj + (size_t)b * 4096 * 2048;
    const unsigned short* xb = xT + (size_t)b * 128 * 4096;

    const int lane = t & 63, wv = t >> 6;
    const int wm = wv & 1, wh = wv >> 1;

    const int a_kp = t >> 3;        // k-pair 0..31
    const int a_mc = t & 7;         // m sub-chunk (4 m's), x4 c-iters

    const int fr = lane & 15, fg = lane >> 4;
    int offA[4][2], offB[4][2];
    #pragma unroll
    for (int f = 0; f < 4; ++f)
        #pragma unroll
        for (int kk = 0; kk < 2; ++kk) {
            offA[f][kk] = foff(wm * 64 + f * 16 + fr, kk * 4 + fg);
            offB[f][kk] = foff(wh * 64 + f * 16 + fr, kk * 4 + fg);
        }

    f32x4_t ar0[4], ar1[4];
    auto LOAD_A = [&](int k0) {      // k0 absolute within batch
        #pragma unroll
        for (int c = 0; c < 4; ++c) {
            const float* p = adjb + (size_t)(k0 + 2 * a_kp) * 2048 + m0 + c * 32 + a_mc * 4;
            ar0[c] = *(const f32x4_t*)(p);
            ar1[c] = *(const f32x4_t*)(p + 2048);
        }
    };
    const int awg = a_kp >> 2, awd = a_kp & 3;
    auto WRITE_A = [&](int buf) {
        #pragma unroll
        for (int c = 0; c < 4; ++c)
            #pragma unroll
            for (int j = 0; j < 4; ++j) {
                const int m = c * 32 + a_mc * 4 + j;
                *(unsigned int*)((char*)(&Al[buf][0]) + m * 128
                    + ((awg ^ (m & 7)) << 4) + awd * 4) = cvtpk(ar0[c][j], ar1[c][j]);
            }
    };

    f32x4_t acc[4][4];
    #pragma unroll
    for (int i = 0; i < 4; ++i)
        #pragma unroll
        for (int j = 0; j < 4; ++j) acc[i][j] = f32x4_t{0.f, 0.f, 0.f, 0.f};

    LOAD_A(nbase);
    stage_B<4096>(xb, nbase, &Bl[0][0], t);
    WRITE_A(0);
    __syncthreads();

    for (int s = 0; s < 16; ++s) {
        const int buf = s & 1;
        if (s < 15) {
            LOAD_A(nbase + (s + 1) * 64);
            stage_B<4096>(xb, nbase + (s + 1) * 64, &Bl[buf ^ 1][0], t);
        }
        bf16x8_t af[4][2];
        #pragma unroll
        for (int mf = 0; mf < 4; ++mf)
            #pragma unroll
            for (int kk = 0; kk < 2; ++kk)
                af[mf][kk] = __builtin_bit_cast(bf16x8_t,
                    *(const u32x4_t*)((const char*)(&Al[buf][0]) + offA[mf][kk]));
        #pragma unroll
        for (int hf = 0; hf < 4; ++hf) {
            bf16x8_t bfr[2];
            #pragma unroll
            for (int kk = 0; kk < 2; ++kk)
                bfr[kk] = __builtin_bit_cast(bf16x8_t,
                    *(const u32x4_t*)((const char*)(&Bl[buf][0]) + offB[hf][kk]));
            #pragma unroll
            for (int mf = 0; mf < 4; ++mf)
                #pragma unroll
                for (int kk = 0; kk < 2; ++kk)
                    acc[mf][hf] = __builtin_amdgcn_mfma_f32_16x16x32_bf16(
                        af[mf][kk], bfr[kk], acc[mf][hf], 0, 0, 0);
        }
        if (s < 15) WRITE_A(buf ^ 1);
        __syncthreads();
    }

    // C: col(lane&15)=h, row((lane>>4)*4+reg)=m; regs = consecutive m.
    float* pb = pLat + (size_t)(nc * 8 + b) * 128 * 2048;
    #pragma unroll
    for (int mf = 0; mf < 4; ++mf) {
        const int mrow = m0 + wm * 64 + mf * 16 + (lane >> 4) * 4;
        #pragma unroll
        for (int hf = 0; hf < 4; ++hf) {
            const int col = wh * 64 + hf * 16 + fr;
            *(f32x4_t*)(pb + (size_t)col * 2048 + mrow) = acc[mf][hf];
        }
    }
}

// latT[b][h][m] = bf16( sum_nc pLat[nc][b][h][m] ) — flat over 2.1M elems
__global__ __launch_bounds__(256) void k2_red(
    const float* __restrict__ pLat,
    unsigned short* __restrict__ latT)
{
    const size_t i4 = ((size_t)blockIdx.x * 256 + threadIdx.x) * 4;
    f32x4_t s = *(const f32x4_t*)(pLat + i4);
    #pragma unroll
    for (int nc = 1; nc < 4; ++nc)
        s += *(const f32x4_t*)(pLat + i4 + (size_t)nc * 2097152);
    u32x2_t o;
    o[0] = cvtpk(s[0], s[1]);
    o[1] = cvtpk(s[2], s[3]);
    *(u32x2_t*)(latT + i4) = o;
}

// ---------------------------------------------------------------------------
// Kernel 3: pRet[kc][b][n][h] = sum_{m in kc} adj[b][n][m] * latT[b][h][m]
// grid 512 = 8b x 32nt(128n) x 2kc(1024m). 4 waves (2h x 2n), wave 64h x 64n.
// MFMA roles swapped: A-op = latT h-frag, B-op = adj n-frag -> C rows = h
// (consecutive regs = consecutive h) -> f32x4 stores to [n][h] layout.
// ---------------------------------------------------------------------------
__global__ __launch_bounds__(256) void k3_ret(
    const float* __restrict__ adj,
    const unsigned short* __restrict__ latT,
    float* __restrict__ pRet)
{
    __shared__ unsigned short Al[2][128 * 64];   // [n][k] bf16
    __shared__ unsigned short Bl[2][128 * 64];   // [h][k] bf16

    const int t   = threadIdx.x;
    const int bid = blockIdx.x;
    const int b   = bid & 7;
    const int r   = bid >> 3;
    const int n0  = (r & 31) << 7;
    const int kc  = r >> 5;
    const int kbase = kc << 10;
    const float* adjb = adj + (size_t)b * 4096 * 2048;
    const unsigned short* lb = latT + (size_t)b * 128 * 2048;

    const int lane = t & 63, wv = t >> 6;
    const int wvh = wv & 1, wvn = wv >> 1;

    const int a_r  = t >> 1;        // n-row 0..127
    const int a_sg = t & 1;         // k-half (32 floats)

    const int fr = lane & 15, fg = lane >> 4;
    int offA[4][2], offB[4][2];     // offA: n-panel rows; offB: h-panel rows
    #pragma unroll
    for (int f = 0; f < 4; ++f)
        #pragma unroll
        for (int kk = 0; kk < 2; ++kk) {
            offA[f][kk] = foff(wvn * 64 + f * 16 + fr, kk * 4 + fg);
            offB[f][kk] = foff(wvh * 64 + f * 16 + fr, kk * 4 + fg);
        }

    f32x4_t ar[8];
    auto LOAD_A = [&](int k0) {      // k0 absolute within batch (m-dim)
        const float* p = adjb + (size_t)(n0 + a_r) * 2048 + k0 + a_sg * 32;
        #pragma unroll
        for (int c = 0; c < 8; ++c) ar[c] = *(const f32x4_t*)(p + c * 4);
    };
    auto WRITE_A = [&](int buf) {
        #pragma unroll
        for (int w = 0; w < 4; ++w) {
            u32x4_t pk;
            pk[0] = cvtpk(ar[2 * w][0], ar[2 * w][1]);
            pk[1] = cvtpk(ar[2 * w][2], ar[2 * w][3]);
            pk[2] = cvtpk(ar[2 * w + 1][0], ar[2 * w + 1][1]);
            pk[3] = cvtpk(ar[2 * w + 1][2], ar[2 * w + 1][3]);
            const int g = a_sg * 4 + w;
            *(u32x4_t*)((char*)(&Al[buf][0]) + a_r * 128
                        + ((g ^ (a_r & 7)) << 4)) = pk;
        }
    };

    f32x4_t acc[4][4];               // [hf][nf]
    #pragma unroll
    for (int i = 0; i < 4; ++i)
        #pragma unroll
        for (int j = 0; j < 4; ++j) acc[i][j] = f32x4_t{0.f, 0.f, 0.f, 0.f};

    LOAD_A(kbase);
    stage_B<2048>(lb, kbase, &Bl[0][0], t);
    WRITE_A(0);
    __syncthreads();

    for (int s = 0; s < 16; ++s) {
        const int buf = s & 1;
        if (s < 15) {
            LOAD_A(kbase + (s + 1) * 64);
            stage_B<2048>(lb, kbase + (s + 1) * 64, &Bl[buf ^ 1][0], t);
        }
        bf16x8_t hfrag[4][2];
        #pragma unroll
        for (int hf = 0; hf < 4; ++hf)
            #pragma unroll
            for (int kk = 0; kk < 2; ++kk)
                hfrag[hf][kk] = __builtin_bit_cast(bf16x8_t,
                    *(const u32x4_t*)((const char*)(&Bl[buf][0]) + offB[hf][kk]));
        #pragma unroll
        for (int nf = 0; nf < 4; ++nf) {
            bf16x8_t nfrag[2];
            #pragma unroll
            for (int kk = 0; kk < 2; ++kk)
                nfrag[kk] = __builtin_bit_cast(bf16x8_t,
                    *(const u32x4_t*)((const char*)(&Al[buf][0]) + offA[nf][kk]));
            #pragma unroll
            for (int hf = 0; hf < 4; ++hf)
                #pragma unroll
                for (int kk = 0; kk < 2; ++kk)
                    acc[hf][nf] = __builtin_amdgcn_mfma_f32_16x16x32_bf16(
                        hfrag[hf][kk], nfrag[kk], acc[hf][nf], 0, 0, 0);
        }
        if (s < 15) WRITE_A(buf ^ 1);
        __syncthreads();
    }

    // C: col(lane&15)=n, row((lane>>4)*4+reg)=h; regs = consecutive h.
    float* pb = pRet + (size_t)(kc * 8 + b) * 4096 * 128;
    #pragma unroll
    for (int nf = 0; nf < 4; ++nf) {
        const int ncol = n0 + wvn * 64 + nf * 16 + fr;
        #pragma unroll
        for (int hf = 0; hf < 4; ++hf) {
            const int hrow = wvh * 64 + hf * 16 + (lane >> 4) * 4;
            *(f32x4_t*)(pb + (size_t)ncol * 128 + hrow) = acc[hf][nf];
        }
    }
}

// ret[b][n][h] = sum_kc pRet[kc][b][n][h] — flat over 4.2M elems
__global__ __launch_bounds__(256) void k3_red(
    const float* __restrict__ pRet,
    float* __restrict__ ret)
{
    const size_t i4 = ((size_t)blockIdx.x * 256 + threadIdx.x) * 4;
    f32x4_t s = *(const f32x4_t*)(pRet + i4);
    s += *(const f32x4_t*)(pRet + i4 + (size_t)4194304);
    *(f32x4_t*)(ret + i4) = s;
}

// ---------------------------------------------------------------------------
extern "C" void kernel_launch(void* const* d_in, const int* in_sizes, int n_in,
                              void* d_out, int out_size, void* d_ws, size_t ws_size,
                              hipStream_t stream) {
    const float* adj    = (const float*)d_in[0];
    const float* embeds = (const float*)d_in[1];
    const int*   ntype  = (const int*)d_in[2];
    const unsigned char* mask8 = (const unsigned char*)d_in[3];
    const float* W      = (const float*)d_in[4];
    const float* bias   = (const float*)d_in[5];
    const float* gamma  = (const float*)d_in[6];
    const float* beta   = (const float*)d_in[7];
    float* ret = (float*)d_out;

    unsigned short* xT   = (unsigned short*)d_ws;                   // 8.39 MB
    unsigned short* latT = xT + (size_t)8 * 128 * 4096;             // 4.19 MB
    float* pLat = (float*)(latT + (size_t)8 * 128 * 2048);          // 33.55 MB
    float* pRet = pLat + (size_t)4 * 8 * 128 * 2048;                // 33.55 MB
    // ws needed: 79.7 MB

    hipLaunchKernelGGL(k1_typed_ln, dim3(256), dim3(256), 0, stream,
                       embeds, ntype, mask8, W, bias, gamma, beta, xT);
    hipLaunchKernelGGL(k2_lat, dim3(512), dim3(256), 0, stream, adj, xT, pLat);
    hipLaunchKernelGGL(k2_red, dim3(2048), dim3(256), 0, stream, pLat, latT);
    hipLaunchKernelGGL(k3_ret, dim3(512), dim3(256), 0, stream, adj, latT, pRet);
    hipLaunchKernelGGL(k3_red, dim3(4096), dim3(256), 0, stream, pRet, ret);
}

// Round 10
// 167.222 us; speedup vs baseline: 1.4525x; 1.4525x over previous
//
#include <hip/hip_runtime.h>
#include <stdint.h>
#include <stddef.h>

// ---------------------------------------------------------------------------
// HHGNN. R10 = R9 with the k0_wtrans store-offset bug fixed:
//  R9 wrote `out + ch*8 - h0 + h` == out + 16*ch for BOTH halves (collision,
//  wrong interleave) -> WT garbage -> absmax 1.95e5. Fix: `out + ch*8`.
// Everything else byte-identical to R9 (k1 = MFMA grouped-by-type linear;
// k2/k3 = R5-exact 215.4us GEMMs) so delta(total) == delta(k1).
// ws: xT 8.39MB + latT 4.19MB + WT 0.43MB.
// ---------------------------------------------------------------------------

typedef float    f32x4_t  __attribute__((ext_vector_type(4)));
typedef __bf16   bf16x8_t __attribute__((ext_vector_type(8)));
typedef unsigned int u32x4_t __attribute__((ext_vector_type(4)));
typedef unsigned int u32x2_t __attribute__((ext_vector_type(2)));

__device__ __forceinline__ unsigned short f2bf(float f) {
    union { float f; unsigned int u; } v; v.f = f;
    unsigned int u = v.u;
    return (unsigned short)((u + 0x7FFFu + ((u >> 16) & 1u)) >> 16);
}

// packed RNE fp32x2 -> bf16x2 (lo=a, hi=b)
__device__ __forceinline__ unsigned int cvtpk(float a, float b) {
    unsigned int r;
    asm("v_cvt_pk_bf16_f32 %0, %1, %2" : "=v"(r) : "v"(a), "v"(b));
    return r;
}

__device__ __forceinline__ bool mask_on(const unsigned char* m, int gid) {
    return (m[gid] | m[(gid >> 2) << 2]) != 0;
}

// byte offset of 16B-granule g in row `row` of a [rows][64] bf16 LDS panel
__device__ __forceinline__ int foff(int row, int g) {
    return row * 128 + (((g) ^ (row & 7)) << 4);
}

// B-panel staging for GEMMs (unchanged from R5)
template<int GSTRIDE>
__device__ __forceinline__ void stage_B(const unsigned short* __restrict__ gb,
                                        int k0, unsigned short* ldsB, int t)
{
    const int l = t & 63, w = t >> 6;
    const int hsub = l >> 3;
    const int csrc = ((l & 7) ^ hsub) << 3;
    #pragma unroll
    for (int i = 0; i < 4; ++i) {
        const int hbase = i * 32 + w * 8;
        const unsigned short* src = gb + (size_t)(hbase + hsub) * GSTRIDE + k0 + csrc;
        unsigned short* dst = ldsB + hbase * 64;
        __builtin_amdgcn_global_load_lds(
            (__attribute__((address_space(1))) void*)src,
            (__attribute__((address_space(3))) void*)dst, 16, 0, 0);
    }
}

// ---------------------------------------------------------------------------
// k0: WT[t][d][h] = bf16(W[t][h][d])  — 13 blocks, one-shot transpose
// ---------------------------------------------------------------------------
__global__ __launch_bounds__(256) void k0_wtrans(
    const float* __restrict__ W, unsigned short* __restrict__ WT)
{
    __shared__ float tile[128][132];
    const int t = threadIdx.x, ty = blockIdx.x;
    const float* Wt = W + (size_t)ty * 128 * 128;
    for (int it = 0; it < 16; ++it) {
        int idx = it * 256 + t;
        int h = idx >> 5, c = (idx & 31) * 4;
        *(float4*)(&tile[h][c]) = *(const float4*)(Wt + h * 128 + c);
    }
    __syncthreads();
    const int d = t >> 1, half = t & 1, h0 = half * 64;
    unsigned short* out = WT + ((size_t)ty * 128 + d) * 128 + h0;
    #pragma unroll
    for (int ch = 0; ch < 8; ++ch) {
        int h = h0 + ch * 8;
        u32x4_t o;
        o[0] = cvtpk(tile[h + 0][d], tile[h + 1][d]);
        o[1] = cvtpk(tile[h + 2][d], tile[h + 3][d]);
        o[2] = cvtpk(tile[h + 4][d], tile[h + 5][d]);
        o[3] = cvtpk(tile[h + 6][d], tile[h + 7][d]);
        *(u32x4_t*)(out + ch * 8) = o;            // FIXED (was +16*ch, colliding)
    }
}

// ---------------------------------------------------------------------------
// k1: typed linear (MFMA) + bias + mask + LayerNorm -> xT bf16 [B][H][N]
// grid 512 = 8b x 64 tiles(64 nodes). 4 waves; wave wv owns d in [32wv,32wv+32).
// ---------------------------------------------------------------------------
__global__ __launch_bounds__(256) void k1_typed_ln(
    const float* __restrict__ embeds,
    const int*   __restrict__ ntype,
    const unsigned char* __restrict__ mask8,
    const unsigned short* __restrict__ WT,
    const float* __restrict__ bias,
    const float* __restrict__ gamma,
    const float* __restrict__ beta,
    unsigned short* __restrict__ xT)
{
    __shared__ unsigned short e_lds[64][136];   // bf16 embeds (pitch 272B)
    __shared__ unsigned short y_lds[64][136];   // bf16 outputs
    __shared__ unsigned short lists[13][64];
    __shared__ int cnt[13];
    __shared__ int grp_ty[32], grp_base[32], grp_n;
    __shared__ unsigned char msk[64];
    __shared__ float g_lds[128], be_lds[128];

    const int t   = threadIdx.x;
    const int bid = blockIdx.x;
    const int b   = bid & 7;
    const int n0  = (bid >> 3) << 6;
    const int gbase = b * 4096 + n0;
    const float* ebase = embeds + (size_t)gbase * 128;

    // stage embeds -> bf16 (thread: node t>>2, 32-float quarter t&3)
    {
        const int n = t >> 2, q = t & 3;
        const float* src = ebase + n * 128 + q * 32;
        #pragma unroll
        for (int c = 0; c < 4; ++c) {
            f32x4_t va = *(const f32x4_t*)(src + c * 8);
            f32x4_t vb = *(const f32x4_t*)(src + c * 8 + 4);
            u32x4_t o;
            o[0] = cvtpk(va[0], va[1]); o[1] = cvtpk(va[2], va[3]);
            o[2] = cvtpk(vb[0], vb[1]); o[3] = cvtpk(vb[2], vb[3]);
            *(u32x4_t*)(&e_lds[n][q * 32 + c * 8]) = o;
        }
    }
    if (t < 128) { g_lds[t] = gamma[t]; be_lds[t] = beta[t]; }
    if (t < 64)  msk[t] = mask_on(mask8, gbase + t) ? 1 : 0;
    if (t < 13)  cnt[t] = 0;
    __syncthreads();

    if (t < 64) {
        int ty = ntype[(size_t)gbase + t];
        int slot = atomicAdd(&cnt[ty], 1);
        lists[ty][slot] = (unsigned short)t;
    }
    __syncthreads();
    if (t == 0) {
        int g = 0;
        for (int ty = 0; ty < 13; ++ty) {
            int c = cnt[ty];
            for (int base = 0; base < c; base += 16) {
                grp_ty[g] = ty; grp_base[g] = base; ++g;
            }
        }
        grp_n = g;
    }
    __syncthreads();

    const int NG   = grp_n;
    const int lane = t & 63, wv = t >> 6;
    const int fr = lane & 15, fg = lane >> 4;
    const int d0 = wv * 32;

    for (int g = 0; g < NG; ++g) {
        const int ty = grp_ty[g], base = grp_base[g];
        const int cend = cnt[ty] - 1;
        const int nodeA = lists[ty][min(base + fr, cend)];

        bf16x8_t afr[4];
        #pragma unroll
        for (int kk = 0; kk < 4; ++kk)
            afr[kk] = __builtin_bit_cast(bf16x8_t,
                *(const u32x4_t*)(&e_lds[nodeA][kk * 32 + fg * 8]));

        const unsigned short* wt = WT + (size_t)ty * 128 * 128;
        f32x4_t acc0 = f32x4_t{0.f, 0.f, 0.f, 0.f};
        f32x4_t acc1 = f32x4_t{0.f, 0.f, 0.f, 0.f};
        #pragma unroll
        for (int kk = 0; kk < 4; ++kk) {
            bf16x8_t b0 = __builtin_bit_cast(bf16x8_t,
                *(const u32x4_t*)(wt + (size_t)(d0 + fr) * 128 + kk * 32 + fg * 8));
            bf16x8_t b1 = __builtin_bit_cast(bf16x8_t,
                *(const u32x4_t*)(wt + (size_t)(d0 + 16 + fr) * 128 + kk * 32 + fg * 8));
            acc0 = __builtin_amdgcn_mfma_f32_16x16x32_bf16(afr[kk], b0, acc0, 0, 0, 0);
            acc1 = __builtin_amdgcn_mfma_f32_16x16x32_bf16(afr[kk], b1, acc1, 0, 0, 0);
        }

        const float bs0 = bias[ty * 128 + d0 + fr];
        const float bs1 = bias[ty * 128 + d0 + 16 + fr];
        #pragma unroll
        for (int j = 0; j < 4; ++j) {
            const int nd = lists[ty][min(base + fg * 4 + j, cend)];
            if (msk[nd]) {
                y_lds[nd][d0 + fr]      = f2bf(acc0[j] + bs0);
                y_lds[nd][d0 + 16 + fr] = f2bf(acc1[j] + bs1);
            } else {
                y_lds[nd][d0 + fr]      = e_lds[nd][d0 + fr];
                y_lds[nd][d0 + 16 + fr] = e_lds[nd][d0 + 16 + fr];
            }
        }
    }
    __syncthreads();

    // LayerNorm in y_lds (bf16 in/out)
    for (int i = 0; i < 16; ++i) {
        const int n = wv + i * 4;
        unsigned int u = *(const unsigned int*)(&y_lds[n][lane * 2]);
        float vx = __builtin_bit_cast(float, u << 16);
        float vy = __builtin_bit_cast(float, u & 0xffff0000u);
        float s = vx + vy;
        float q = vx * vx + vy * vy;
        #pragma unroll
        for (int mw = 32; mw >= 1; mw >>= 1) {
            s += __shfl_xor(s, mw);
            q += __shfl_xor(q, mw);
        }
        const float mu  = s * 0.0078125f;
        const float var = q * 0.0078125f - mu * mu;
        const float r   = rsqrtf(var + 1e-5f);
        const float ox = (vx - mu) * r * g_lds[lane * 2]     + be_lds[lane * 2];
        const float oy = (vy - mu) * r * g_lds[lane * 2 + 1] + be_lds[lane * 2 + 1];
        *(unsigned int*)(&y_lds[n][lane * 2]) = cvtpk(ox, oy);
    }
    __syncthreads();

    // transposed store (coalesced along n)
    const int nl = t & 63, hg = t >> 6;
    unsigned short* xrow = xT + (size_t)b * 128 * 4096 + n0 + nl;
    for (int i = 0; i < 32; ++i) {
        const int h = hg * 32 + i;
        xrow[(size_t)h * 4096] = y_lds[nl][h];
    }
}

// ---------------------------------------------------------------------------
// Kernel 2 (R5-exact): latT[b][h][m] = sum_n adj[b][n][m] * x[b][n][h]
// ---------------------------------------------------------------------------
__global__ __launch_bounds__(256) void k2_lat(
    const float* __restrict__ adj,
    const unsigned short* __restrict__ xT,
    unsigned short* __restrict__ latT)
{
    __shared__ unsigned short Al[2][32 * 64];
    __shared__ unsigned short Bl[2][128 * 64];

    const int t   = threadIdx.x;
    const int bid = blockIdx.x;
    const int b   = bid & 7;
    const int m0  = (bid >> 3) << 5;
    const float* adjb = adj + (size_t)b * 4096 * 2048;
    const unsigned short* xb = xT + (size_t)b * 128 * 4096;

    const int lane = t & 63, wv = t >> 6;
    const int wm = wv & 1, wh = wv >> 1;

    const int a_kp = t >> 3;
    const int a_m  = (t & 7) << 2;

    const int fr = lane & 15, fg = lane >> 4;
    int offA[2], offB[4][2];
    #pragma unroll
    for (int kk = 0; kk < 2; ++kk) offA[kk] = foff(wm * 16 + fr, kk * 4 + fg);
    #pragma unroll
    for (int j = 0; j < 4; ++j)
        #pragma unroll
        for (int kk = 0; kk < 2; ++kk)
            offB[j][kk] = foff(wh * 64 + j * 16 + fr, kk * 4 + fg);

    f32x4_t ar0, ar1;
    auto LOAD_A = [&](int k0) {
        const float* p = adjb + (size_t)(k0 + a_kp * 2) * 2048 + m0 + a_m;
        ar0 = *(const f32x4_t*)(p);
        ar1 = *(const f32x4_t*)(p + 2048);
    };
    auto WRITE_A = [&](int buf) {
        const int g = a_kp >> 2, wrd = a_kp & 3;
        #pragma unroll
        for (int j = 0; j < 4; ++j) {
            const int m = a_m + j;
            unsigned int pk = cvtpk(ar0[j], ar1[j]);
            *(unsigned int*)((char*)(&Al[buf][0]) + m * 128 + ((g ^ (m & 7)) << 4) + wrd * 4) = pk;
        }
    };

    f32x4_t acc[4];
    #pragma unroll
    for (int j = 0; j < 4; ++j) acc[j] = f32x4_t{0.f, 0.f, 0.f, 0.f};

    LOAD_A(0);
    stage_B<4096>(xb, 0, &Bl[0][0], t);
    WRITE_A(0);
    __syncthreads();

    for (int s = 0; s < 64; ++s) {
        const int buf = s & 1;
        if (s < 63) {
            LOAD_A((s + 1) * 64);
            stage_B<4096>(xb, (s + 1) * 64, &Bl[buf ^ 1][0], t);
        }
        bf16x8_t af[2];
        #pragma unroll
        for (int kk = 0; kk < 2; ++kk)
            af[kk] = __builtin_bit_cast(bf16x8_t,
                *(const u32x4_t*)((const char*)(&Al[buf][0]) + offA[kk]));
        #pragma unroll
        for (int j = 0; j < 4; ++j) {
            #pragma unroll
            for (int kk = 0; kk < 2; ++kk) {
                bf16x8_t bfj = __builtin_bit_cast(bf16x8_t,
                    *(const u32x4_t*)((const char*)(&Bl[buf][0]) + offB[j][kk]));
                acc[j] = __builtin_amdgcn_mfma_f32_16x16x32_bf16(af[kk], bfj, acc[j], 0, 0, 0);
            }
        }
        if (s < 63) WRITE_A(buf ^ 1);
        __syncthreads();
    }

    const int mrow = m0 + wm * 16 + (lane >> 4) * 4;
    #pragma unroll
    for (int j = 0; j < 4; ++j) {
        int col = wh * 64 + j * 16 + fr;
        unsigned int o0 = cvtpk(acc[j][0], acc[j][1]);
        unsigned int o1 = cvtpk(acc[j][2], acc[j][3]);
        unsigned int* dst = (unsigned int*)(latT + (size_t)(b * 128 + col) * 2048 + mrow);
        dst[0] = o0; dst[1] = o1;
    }
}

// ---------------------------------------------------------------------------
// Kernel 3 (R5-exact): ret[b][n][h] = sum_m adj[b][n][m] * latT[b][h][m]
// ---------------------------------------------------------------------------
__global__ __launch_bounds__(256) void k3_ret(
    const float* __restrict__ adj,
    const unsigned short* __restrict__ latT,
    float* __restrict__ ret)
{
    __shared__ unsigned short Al[2][32 * 64];
    __shared__ unsigned short Bl[2][128 * 64];

    const int t   = threadIdx.x;
    const int bid = blockIdx.x;
    const int b   = bid & 7;
    const int n0  = (bid >> 3) << 5;
    const float* adjb = adj + (size_t)b * 4096 * 2048;
    const unsigned short* lb = latT + (size_t)b * 128 * 2048;

    const int lane = t & 63, wv = t >> 6;
    const int wn = wv & 1, wh = wv >> 1;

    const int a_r = t >> 3;
    const int a_c = t & 7;

    const int fr = lane & 15, fg = lane >> 4;
    int offA[2], offB[4][2];
    #pragma unroll
    for (int kk = 0; kk < 2; ++kk) offA[kk] = foff(wn * 16 + fr, kk * 4 + fg);
    #pragma unroll
    for (int j = 0; j < 4; ++j)
        #pragma unroll
        for (int kk = 0; kk < 2; ++kk)
            offB[j][kk] = foff(wh * 64 + j * 16 + fr, kk * 4 + fg);

    f32x4_t ar0, ar1;
    auto LOAD_A = [&](int k0) {
        const float* p = adjb + (size_t)(n0 + a_r) * 2048 + k0 + a_c * 8;
        ar0 = *(const f32x4_t*)(p);
        ar1 = *(const f32x4_t*)(p + 4);
    };
    auto WRITE_A = [&](int buf) {
        u32x4_t pk;
        pk[0] = cvtpk(ar0[0], ar0[1]);
        pk[1] = cvtpk(ar0[2], ar0[3]);
        pk[2] = cvtpk(ar1[0], ar1[1]);
        pk[3] = cvtpk(ar1[2], ar1[3]);
        *(u32x4_t*)((char*)(&Al[buf][0]) + a_r * 128 + ((a_c ^ (a_r & 7)) << 4)) = pk;
    };

    f32x4_t acc[4];
    #pragma unroll
    for (int j = 0; j < 4; ++j) acc[j] = f32x4_t{0.f, 0.f, 0.f, 0.f};

    LOAD_A(0);
    stage_B<2048>(lb, 0, &Bl[0][0], t);
    WRITE_A(0);
    __syncthreads();

    for (int s = 0; s < 32; ++s) {
        const int buf = s & 1;
        if (s < 31) {
            LOAD_A((s + 1) * 64);
            stage_B<2048>(lb, (s + 1) * 64, &Bl[buf ^ 1][0], t);
        }
        bf16x8_t af[2];
        #pragma unroll
        for (int kk = 0; kk < 2; ++kk)
            af[kk] = __builtin_bit_cast(bf16x8_t,
                *(const u32x4_t*)((const char*)(&Al[buf][0]) + offA[kk]));
        #pragma unroll
        for (int j = 0; j < 4; ++j) {
            #pragma unroll
            for (int kk = 0; kk < 2; ++kk) {
                bf16x8_t bfj = __builtin_bit_cast(bf16x8_t,
                    *(const u32x4_t*)((const char*)(&Bl[buf][0]) + offB[j][kk]));
                acc[j] = __builtin_amdgcn_mfma_f32_16x16x32_bf16(af[kk], bfj, acc[j], 0, 0, 0);
            }
        }
        if (s < 31) WRITE_A(buf ^ 1);
        __syncthreads();
    }

    const int nrow = n0 + wn * 16 + (lane >> 4) * 4;
    #pragma unroll
    for (int j = 0; j < 4; ++j) {
        int col = wh * 64 + j * 16 + fr;
        #pragma unroll
        for (int jj = 0; jj < 4; ++jj) {
            ret[((size_t)b * 4096 + nrow + jj) * 128 + col] = acc[j][jj];
        }
    }
}

// ---------------------------------------------------------------------------
extern "C" void kernel_launch(void* const* d_in, const int* in_sizes, int n_in,
                              void* d_out, int out_size, void* d_ws, size_t ws_size,
                              hipStream_t stream) {
    const float* adj    = (const float*)d_in[0];
    const float* embeds = (const float*)d_in[1];
    const int*   ntype  = (const int*)d_in[2];
    const unsigned char* mask8 = (const unsigned char*)d_in[3];
    const float* W      = (const float*)d_in[4];
    const float* bias   = (const float*)d_in[5];
    const float* gamma  = (const float*)d_in[6];
    const float* beta   = (const float*)d_in[7];
    float* ret = (float*)d_out;

    unsigned short* xT   = (unsigned short*)d_ws;                   // 8.39 MB
    unsigned short* latT = xT + (size_t)8 * 128 * 4096;             // 4.19 MB
    unsigned short* WT   = latT + (size_t)8 * 128 * 2048;           // 0.43 MB
    // ws needed: 13.0 MB

    hipLaunchKernelGGL(k0_wtrans, dim3(13), dim3(256), 0, stream, W, WT);
    hipLaunchKernelGGL(k1_typed_ln, dim3(512), dim3(256), 0, stream,
                       embeds, ntype, mask8, WT, bias, gamma, beta, xT);
    hipLaunchKernelGGL(k2_lat, dim3(512), dim3(256), 0, stream, adj, xT, latT);
    hipLaunchKernelGGL(k3_ret, dim3(1024), dim3(256), 0, stream, adj, latT, ret);
}